// Round 3
// baseline (390.319 us; speedup 1.0000x reference)
//
#include <hip/hip_runtime.h>
#include <stdint.h>

#define B_ 16
#define C_ 64
#define H_ 112
#define W_ 112
#define N_ 256

typedef __attribute__((ext_vector_type(8))) short short8;
typedef __attribute__((ext_vector_type(4))) float floatx4;

typedef __attribute__((address_space(1))) const uint32_t gas_u32;
typedef __attribute__((address_space(3))) uint32_t las_u32;

__device__ __forceinline__ uint32_t f2bf_bits(float f) {
  uint32_t u = __float_as_uint(f);
  return (u + 0x7fffu + ((u >> 16) & 1u)) >> 16;  // RNE f32 -> bf16 bits
}

// NCHW f32 -> [b][i][j][c] packed uint32: low16 = bf16(x), high16 = bf16(x^2)
__global__ __launch_bounds__(256) void xform_x(const float* __restrict__ x,
                                               uint32_t* __restrict__ xq) {
  __shared__ float ls[64][113];  // +1 pad: odd stride -> conflict-free transpose read
  int bi = blockIdx.x;
  int b = bi / H_, i = bi % H_;
  const float* xbase = x + ((size_t)b * C_) * (H_ * W_) + (size_t)i * W_;
  for (int idx = threadIdx.x; idx < C_ * W_; idx += 256) {
    int c = idx / W_, j = idx - c * W_;
    ls[c][j] = xbase[(size_t)c * (H_ * W_) + j];
  }
  __syncthreads();
  uint32_t* orow = xq + ((size_t)(b * H_ + i)) * (W_ * C_);
  for (int idx = threadIdx.x; idx < W_ * C_; idx += 256) {
    int j = idx >> 6, c = idx & 63;
    float v = ls[c][j];
    float v2 = v * v;
    orow[idx] = f2bf_bits(v) | (f2bf_bits(v2) << 16);
  }
}

// Weights -> Wg[slice = cgq(4)*9+tap][dw(n,p)] uint32 pairs:
//   low16 = bf16(2*|w|*t) (multiplies x), high16 = bf16(-|w|) (multiplies x^2)
// cgq = 16-channel group (c>>4), p = c&15 (K position within slice).
// dw(n,p) = (n>>4)*256 + (p>>2)*64 + (n&15)*4 + (p&3):
//   A-frag read quad = l4*16+l15 -> distinct within each 16-lane phase group
//   (fixes the 4cy/read b128 conflict measured in r2; staging is a linear copy).
// Also computes cN[n] = sum |w| t^2 (fused, one block per n).
__global__ __launch_bounds__(64) void prep_wc(const float* __restrict__ sw,
                                              const float* __restrict__ tp,
                                              uint32_t* __restrict__ Wg,
                                              float* __restrict__ cN) {
  int n = blockIdx.x, c = threadIdx.x;  // c = 0..63
  int cgq = c >> 4, pos = c & 15;
  const float* swp = sw + (size_t)(n * C_ + c) * 9;
  const float* tpp = tp + (size_t)(n * C_ + c) * 9;
  int dw = ((n >> 4) << 8) + ((pos >> 2) << 6) + ((n & 15) << 2) + (pos & 3);
  float s = 0.f;
#pragma unroll
  for (int tap = 0; tap < 9; ++tap) {
    float w = fabsf(swp[tap]);
    float t = tpp[tap];
    s += w * t * t;
    uint32_t v = f2bf_bits(2.0f * w * t) | (f2bf_bits(-w) << 16);
    Wg[(size_t)(cgq * 9 + tap) * (N_ * 16) + dw] = v;
  }
#pragma unroll
  for (int off = 32; off > 0; off >>= 1) s += __shfl_down(s, off);
  if (c == 0) cN[n] = s;
}

// Output tile: 128 n x 256 pixels (16x16). 512 threads = 8 waves, each 64n x 4r x 16c.
// r2 post-mortem: 36 full-drain __syncthreads/block (vmcnt(0)+lgkmcnt(0) each) were
// the residual stall (no pipe >32% busy). This round: T3/T4-style counted pipeline.
//   - ws quad-buffered (4 x 8KB), global_load_lds prefetch depth 2,
//     per-step barrier = s_waitcnt vmcnt(1) + raw s_barrier (never vmcnt(0) midloop)
//   - K staged in 16-channel groups (cgq): xs = 324 sites x 64B @ 80B stride
//     (5 quads, coprime 32 -> bfr reads conflict-free); xs 25.9KB + ws 32KB < 64KB
//   - A-frag layout transposed in Wg (see prep_wc) -> af reads conflict-free
// Buffer-reuse audit: buf[(s+2)&3] written at step s was last read at step s-2,
// >= 2 barrier rendezvous earlier; xs rewritten only after a full __syncthreads.
__global__ __launch_bounds__(512, 4) void sim_main(const uint32_t* __restrict__ xq,
                                                   const uint32_t* __restrict__ Wg,
                                                   const float* __restrict__ cN,
                                                   float* __restrict__ out) {
  __shared__ uint32_t xs[324 * 20];  // 18x18 sites x 16ch(64B), stride 80B
  __shared__ uint32_t ws[4 * 2048];  // 4 x 8KB weight slice ring

  int bx = blockIdx.x;
  int nb = bx & 1;
  bx >>= 1;
  int b = bx / 49;
  int rem = bx - b * 49;
  int rt = rem / 7, ct = rem - rt * 7;
  int r0 = rt * 16, c0 = ct * 16;
  int tid = threadIdx.x;
  int lane = tid & 63, wv = tid >> 6;
  int wn = wv & 1, wp = wv >> 1;  // wn: which 64-n half, wp: which 4-row group
  int l15 = lane & 15, l4 = lane >> 4;

  floatx4 acc[4][4];  // [nt][pt]; D row = n (l4*4+reg), D col = pixel (l15)
#pragma unroll
  for (int a = 0; a < 4; ++a)
#pragma unroll
    for (int p = 0; p < 4; ++p) acc[a][p] = (floatx4){0.f, 0.f, 0.f, 0.f};

  const uint32_t* xim = xq + (size_t)b * (H_ * W_ * C_);
  const uint32_t* wbase = Wg + nb * 2048;  // + s*4096 per slice

  // stage 18x18 halo sites, 16 channels (64B) each for cgq, zero-filled OOB
  auto stage_xs = [&](int cgq) {
    for (int idx = tid; idx < 324 * 4; idx += 512) {
      int s = idx >> 2, ch = idx & 3;
      int row = s / 18, col = s - row * 18;
      int gi = r0 - 1 + row, gj = c0 - 1 + col;
      uint4 v = make_uint4(0u, 0u, 0u, 0u);
      if ((unsigned)gi < (unsigned)H_ && (unsigned)gj < (unsigned)W_)
        v = *(const uint4*)(xim + ((size_t)(gi * W_ + gj)) * C_ + cgq * 16 + ch * 4);
      *(uint4*)(&xs[s * 20 + ch * 4]) = v;
    }
  };
  // stage weight slice s -> ws ring slot s&3 (1KB linear per wave; lds dest is
  // wave-uniform base + lane*16, global src per-lane)
  auto stage_w = [&](int s) {
    const uint32_t* g = wbase + (size_t)s * 4096 + wv * 256 + lane * 4;
    uint32_t* l = &ws[(s & 3) * 2048 + wv * 256];
    __builtin_amdgcn_global_load_lds((gas_u32*)g, (las_u32*)l, 16, 0, 0);
  };

  // prologue: xs for cgq=0, slices 0 and 1 in flight -> full drain once
  stage_xs(0);
  stage_w(0);
  stage_w(1);
  __syncthreads();

  int awb = wn * 1024 + l4 * 64 + l15 * 4;  // A-frag dword base within slice

#pragma unroll 1
  for (int s = 0; s < 36; ++s) {  // s = cgq*9 + tap
    if (s && s % 9 == 0) {        // cgq boundary: old-xs readers done (barrier @s-1)
      stage_xs(s / 9);
      __syncthreads();  // drains everything incl. slice s+1 (issued at s-2)
    }
    if (s < 34) stage_w(s + 2);  // ring prefetch, 2 deep
    int tap = s % 9;
    int dp = tap / 3, dq = tap - dp * 3;
    int buf = s & 3;

    short8 af[4], bfr[4];
#pragma unroll
    for (int nt = 0; nt < 4; ++nt)
      af[nt] = *(const short8*)(&ws[buf * 2048 + awb + nt * 256]);
#pragma unroll
    for (int pt = 0; pt < 4; ++pt) {
      int st = (wp * 4 + pt + dp) * 18 + l15 + dq;
      bfr[pt] = *(const short8*)(&xs[st * 20 + l4 * 4]);
    }
#pragma unroll
    for (int nt = 0; nt < 4; ++nt)
#pragma unroll
      for (int pt = 0; pt < 4; ++pt)
        acc[nt][pt] =
            __builtin_amdgcn_mfma_f32_16x16x32_bf16(af[nt], bfr[pt], acc[nt][pt], 0, 0, 0);

    if (s < 35) {  // counted-vmcnt barrier: slice s+1 landed, s+2 stays in flight
      if (s < 34)
        asm volatile("s_waitcnt vmcnt(1)" ::: "memory");
      else
        asm volatile("s_waitcnt vmcnt(0)" ::: "memory");
      __builtin_amdgcn_s_barrier();
      asm volatile("" ::: "memory");  // no reads hoisted above the rendezvous
    }
  }

  // epilogue: out[b][n][r][col] = acc - const[n]; lanes 0..15 -> consecutive cols
#pragma unroll
  for (int nt = 0; nt < 4; ++nt) {
#pragma unroll
    for (int v = 0; v < 4; ++v) {
      int n = nb * 128 + wn * 64 + nt * 16 + l4 * 4 + v;
      float cv = cN[n];
#pragma unroll
      for (int pt = 0; pt < 4; ++pt) {
        int r = r0 + wp * 4 + pt;
        int col = c0 + l15;
        out[(((size_t)b * N_ + n) * H_ + r) * W_ + col] = acc[nt][pt][v] - cv;
      }
    }
  }
}

extern "C" void kernel_launch(void* const* d_in, const int* in_sizes, int n_in,
                              void* d_out, int out_size, void* d_ws, size_t ws_size,
                              hipStream_t stream) {
  const float* x = (const float*)d_in[0];
  const float* sw = (const float*)d_in[1];
  const float* tp = (const float*)d_in[2];
  float* out = (float*)d_out;

  // workspace layout
  const size_t xq_bytes = (size_t)B_ * H_ * W_ * C_ * 4;  // 51,380,224
  const size_t wg_bytes = (size_t)36 * N_ * 16 * 4;       // 589,824
  uint32_t* xq = (uint32_t*)d_ws;
  uint32_t* Wg = (uint32_t*)((char*)d_ws + xq_bytes);
  float* cN = (float*)((char*)d_ws + xq_bytes + wg_bytes);

  xform_x<<<dim3(B_ * H_), dim3(256), 0, stream>>>(x, xq);
  prep_wc<<<dim3(N_), dim3(64), 0, stream>>>(sw, tp, Wg, cN);
  sim_main<<<dim3(2 * B_ * 7 * 7), dim3(512), 0, stream>>>(xq, Wg, cN, out);
}